// Round 2
// baseline (188.097 us; speedup 1.0000x reference)
//
#include <hip/hip_runtime.h>
#include <math.h>

// Problem constants (B, N, L, D) from the reference setup_inputs().
#define BSZ 64
#define NN  128
#define LL  64
#define DD  768
#define NEGV (-9e9f)

#define TQ (BSZ * NN * DD / 4)   // text float4 count  = 1572864
#define IQ (BSZ * LL * DD / 4)   // image float4 count =  786432

typedef _Float16 f16x8 __attribute__((ext_vector_type(8)));  // 8 f16 = 4 VGPRs
typedef __attribute__((ext_vector_type(4))) float f32x4;     // MFMA 16x16 accum

// async 16B global -> LDS (dest = wave-uniform base + lane*16)
__device__ __forceinline__ void gl_lds16(const void* g, void* l) {
    __builtin_amdgcn_global_load_lds(
        (const __attribute__((address_space(1))) void*)g,
        (__attribute__((address_space(3))) void*)l, 16, 0, 0);
}

// ---------------------------------------------------------------------------
// Kernel 0: fp32 -> fp16 (RTN). Error 2^-11 relative; N(0,1) inputs, no
// range issues.
// ---------------------------------------------------------------------------
__global__ __launch_bounds__(256) void k_prep(
    const float4* __restrict__ t4, const float4* __restrict__ g4,
    ushort4* __restrict__ A, ushort4* __restrict__ B)
{
    int id = blockIdx.x * 256 + threadIdx.x;
    const float4* src; ushort4* dst; int idx;
    if (id < TQ) { src = t4; dst = A; idx = id; }
    else         { src = g4; dst = B; idx = id - TQ; }
    float4 x = src[idx];
    _Float16 h0 = (_Float16)x.x, h1 = (_Float16)x.y;
    _Float16 h2 = (_Float16)x.z, h3 = (_Float16)x.w;
    ushort4 o;
    o.x = __builtin_bit_cast(unsigned short, h0);
    o.y = __builtin_bit_cast(unsigned short, h1);
    o.z = __builtin_bit_cast(unsigned short, h2);
    o.w = __builtin_bit_cast(unsigned short, h3);
    dst[idx] = o;
}

// ---------------------------------------------------------------------------
// Stage one 32 KB chunk (A: 128 rows x 64 k f16, B: 128 rows x 64 k) into LDS.
// LDS slot for (r, k8): r*8 + (k8 ^ (r&7)), 16B per slot (XOR bank swizzle).
// global_load_lds dest = wave-uniform base + lane*16; slot index is linear
// in (call, wave, lane): slot = c*256 + wave*64 + lane.
// ---------------------------------------------------------------------------
__device__ __forceinline__ void stage_chunk(
    const unsigned short* __restrict__ pa, const unsigned short* __restrict__ pb,
    int k0, char* buf, int wave, int lane)
{
    int rsub = lane >> 3;     // 0..7
    int k8s  = lane & 7;
#pragma unroll
    for (int c = 0; c < 4; c++) {
        int r  = c * 32 + wave * 8 + rsub;
        int k8 = k8s ^ (r & 7);
        gl_lds16(pa + (size_t)r * DD + k0 + k8 * 8, buf + c * 4096 + wave * 1024);
        gl_lds16(pb + (size_t)r * DD + k0 + k8 * 8, buf + 16384 + c * 4096 + wave * 1024);
    }
}

// ---------------------------------------------------------------------------
// Kernel 1: one block per (i, jj) where jj covers j = {2jj, 2jj+1}.
// C[128][128] = text[i] @ [image[j0]; image[j1]]^T, single-pass fp16 MFMA,
// LDS-staged via global_load_lds, double-buffered, 12 chunks of BK=64.
// Epilogue: masked softmax reductions, S + diagonal W.
// R1 edit: phase-2 col softmax uses all 256 threads (2 per column, partial
// scans combined via LDS); diagonal W reuses phase-1 row stats (bit-exact).
// ---------------------------------------------------------------------------
__global__ __launch_bounds__(256, 2) void k_scores(
    const unsigned short* __restrict__ A, const unsigned short* __restrict__ B,
    const int* __restrict__ tmask, const int* __restrict__ imask,
    float* __restrict__ S, float* __restrict__ W)
{
    union SmemU {
        char  stage[2][32768];     // [buf][A 16KB | B 16KB]
        float Cs[NN][129];         // 66 KB epilogue tile (stride 129: 2-way free)
    };
    __shared__ SmemU u;
    __shared__ float tmi[NN];
    __shared__ float imj[NN];      // 128 cols = two j's
    __shared__ float rowred[256];
    __shared__ float colred[NN];
    __shared__ float rowm[256], rowsm[256];          // phase-1 row stats stash
    __shared__ float colm[256], colp1[256], colp2[256];  // phase-2 partials

    // 4x4 block-group swizzle for L2 locality (~1.6 MB working set / group)
    const int bid = blockIdx.x;
    const int grp = bid >> 4, idx = bid & 15;
    const int i  = (grp >> 3) * 4 + (idx >> 2);   // 0..63
    const int jj = (grp & 7) * 4 + (idx & 3);     // 0..31
    const int j0 = jj * 2;

    const int tid  = threadIdx.x;
    const int wave = tid >> 6;
    const int lane = tid & 63;
    const int quad = lane >> 4;
    const int l15  = lane & 15;
    const int rh   = wave & 1;     // row half (64 rows)
    const int ch   = wave >> 1;    // col half (64 cols)

    if (tid < NN) {
        tmi[tid] = tmask[i * NN + tid] ? 1.f : 0.f;
        imj[tid] = imask[j0 * LL + tid] ? 1.f : 0.f;   // two j's contiguous
    }

    const unsigned short* pa = A + (size_t)i * NN * DD;
    const unsigned short* pb = B + (size_t)j0 * LL * DD;

    f32x4 acc[4][4];
    const f32x4 zf = {0.f, 0.f, 0.f, 0.f};
#pragma unroll
    for (int tr = 0; tr < 4; tr++)
#pragma unroll
        for (int tc = 0; tc < 4; tc++) acc[tr][tc] = zf;

    stage_chunk(pa, pb, 0, u.stage[0], wave, lane);
    __syncthreads();

    for (int c = 0; c < 12; c++) {
        if (c + 1 < 12)
            stage_chunk(pa, pb, (c + 1) << 6, u.stage[(c + 1) & 1], wave, lane);
        const char* Ab = u.stage[c & 1];
        const char* Bb = Ab + 16384;
#pragma unroll
        for (int s = 0; s < 2; s++) {
            int k8q = s * 4 + quad;
            int sw  = k8q ^ (l15 & 7);
            f16x8 af[4], bfr[4];
#pragma unroll
            for (int t = 0; t < 4; t++) {
                int row = rh * 64 + t * 16 + l15;
                af[t]  = *(const f16x8*)(Ab + ((row << 3) + sw) * 16);
                int col = ch * 64 + t * 16 + l15;
                bfr[t] = *(const f16x8*)(Bb + ((col << 3) + sw) * 16);
            }
#pragma unroll
            for (int tr = 0; tr < 4; tr++)
#pragma unroll
                for (int tc = 0; tc < 4; tc++)
                    acc[tr][tc] = __builtin_amdgcn_mfma_f32_16x16x32_f16(
                        af[tr], bfr[tc], acc[tr][tc], 0, 0, 0);
        }
        __syncthreads();
    }

    // masked att -> Cs.  att = (mask && dot != 0) ? dot : NEG
    // C/D layout per 16x16 tile: row = quad*4 + rr, col = l15
#pragma unroll
    for (int tr = 0; tr < 4; tr++) {
        int rb = rh * 64 + tr * 16 + quad * 4;
#pragma unroll
        for (int tc = 0; tc < 4; tc++) {
            int col = ch * 64 + tc * 16 + l15;
            float im = imj[col];
#pragma unroll
            for (int rr = 0; rr < 4; rr++) {
                int row = rb + rr;
                float v = acc[tr][tc][rr];
                bool keep = (tmi[row] != 0.f) && (im != 0.f) && (v != 0.f);
                u.Cs[row][col] = keep ? v : NEGV;
            }
        }
    }
    __syncthreads();

    // phase 1: row softmax over l for each (jh, n) -- all 256 threads
    {
        int jh = tid >> 7, n = tid & 127;
        const float* Crow = &u.Cs[n][jh * 64];
        float m = -INFINITY;
        for (int l = 0; l < LL; l++) m = fmaxf(m, Crow[l]);
        float ssum = 0.f, ws = 0.f;
        for (int l = 0; l < LL; l++) {
            float v = Crow[l];
            float e = __expf(v - m);      // all-NEG row -> uniform
            ssum += e;
            ws += imj[jh * 64 + l] * e * v;
        }
        rowm[tid] = m;                    // stash for diagonal W (bit-exact)
        rowsm[tid] = ssum;
        rowred[tid] = tmi[n] * (ws / ssum);
    }
    __syncthreads();

    // phase 2: col softmax, ALL 256 threads, 2 per column (split over n-halves)
    {
        int c  = tid & 127;              // column 0..127
        int n0 = (tid >> 7) * 64;        // row half start
        float m = -INFINITY;
        for (int n = n0; n < n0 + 64; n++) m = fmaxf(m, u.Cs[n][c]);
        colm[tid] = m;
        __syncthreads();
        m = fmaxf(colm[tid], colm[tid ^ 128]);
        float ssum = 0.f, ws = 0.f;
        for (int n = n0; n < n0 + 64; n++) {
            float v = u.Cs[n][c];
            float e = __expf(v - m);
            ssum += e;
            ws += tmi[n] * e * v;
        }
        colp1[tid] = ssum;
        colp2[tid] = ws;
    }
    __syncthreads();
    if (tid < NN) {
        float ssum = colp1[tid] + colp1[tid + 128];
        float ws   = colp2[tid] + colp2[tid + 128];
        colred[tid] = imj[tid] * (ws / ssum);
    }

    // diagonal W (32/2048 blocks): write pass only, reusing phase-1 stats.
    // Phase 1 scanned the same Crow in the same order -> m, ssum bit-identical
    // to the old recompute.
    if (jj == (i >> 1) && tid < NN) {
        int jh = i & 1;
        int n = tid;
        float m   = rowm[jh * 128 + n];
        float inv = 1.f / rowsm[jh * 128 + n];
        const float* Crow = &u.Cs[n][jh * 64];
        float* Wb = W + (size_t)i * LL * NN;
        for (int l = 0; l < LL; l++)
            Wb[(size_t)l * NN + n] = __expf(Crow[l] - m) * inv;  // coalesced over n
    }
    __syncthreads();

    // S[i][j0+jh] = (sum_n rowred + sum_l colred) / N   (waves 0,1)
    if (tid < NN) {
        int jh = tid >> 6, t = tid & 63;
        float p = rowred[jh * 128 + t] + rowred[jh * 128 + 64 + t] + colred[jh * 64 + t];
#pragma unroll
        for (int off = 32; off; off >>= 1) p += __shfl_down(p, off);
        if (t == 0) S[i * BSZ + j0 + jh] = p / (float)NN;
    }
}

// ---------------------------------------------------------------------------
// Kernel 2: text_emb_i2s[b,n,d] = sum_l W[b][l][n] * img[b][l][d]
// Grid: (64 b, 3 d-chunks of 256, 8 n-groups of 16).  W chunk staged in LDS.
// ---------------------------------------------------------------------------
__global__ __launch_bounds__(256) void k_i2s(
    const float* __restrict__ W, const float* __restrict__ img,
    float* __restrict__ out)
{
    __shared__ float Ws[LL][16];   // 4 KB
    const int b  = blockIdx.x;
    const int ng = blockIdx.z * 16;
    const int d  = blockIdx.y * 256 + threadIdx.x;
    const float* Wb = W + (size_t)b * LL * NN;

    {   // stage W[l][ng..ng+15]: 1024 floats, 4 per thread
        int t4 = threadIdx.x * 4;
        int l = t4 >> 4, noff = t4 & 15;
        float4 w = *(const float4*)(Wb + (size_t)l * NN + ng + noff);
        Ws[l][noff + 0] = w.x; Ws[l][noff + 1] = w.y;
        Ws[l][noff + 2] = w.z; Ws[l][noff + 3] = w.w;
    }
    __syncthreads();

    const float* ib = img + (size_t)b * LL * DD;
    float* ob = out + 1 + (size_t)b * NN * DD + (size_t)ng * DD;  // slot 0 = loss

    float acc[16];
#pragma unroll
    for (int q = 0; q < 16; q++) acc[q] = 0.f;
    for (int l = 0; l < LL; l++) {
        float g = ib[(size_t)l * DD + d];
#pragma unroll
        for (int q = 0; q < 16; q++)
            acc[q] = fmaf(Ws[l][q], g, acc[q]);   // Ws read is broadcast
    }
#pragma unroll
    for (int q = 0; q < 16; q++)
        ob[(size_t)q * DD + d] = acc[q];
}

// ---------------------------------------------------------------------------
// Kernel 3: loss = -sum_i( 2*S[i,i] - lse_row_i(S) - lse_col_i(S) ) / B
// ---------------------------------------------------------------------------
__global__ void k_loss(const float* __restrict__ S, float* __restrict__ out)
{
    const int t = threadIdx.x;  // 0..63
    float diag = S[t * BSZ + t];
    float m1 = -INFINITY, m2 = -INFINITY;
    for (int jj = 0; jj < BSZ; jj++) {
        m1 = fmaxf(m1, S[t * BSZ + jj]);
        m2 = fmaxf(m2, S[jj * BSZ + t]);
    }
    float s1 = 0.f, s2 = 0.f;
    for (int jj = 0; jj < BSZ; jj++) {
        s1 += __expf(S[t * BSZ + jj] - m1);
        s2 += __expf(S[jj * BSZ + t] - m2);
    }
    float p = 2.f * diag - (m1 + logf(s1)) - (m2 + logf(s2));
#pragma unroll
    for (int off = 32; off; off >>= 1) p += __shfl_down(p, off);
    if (t == 0) out[0] = -p / (float)BSZ;
}

// ---------------------------------------------------------------------------
extern "C" void kernel_launch(void* const* d_in, const int* in_sizes, int n_in,
                              void* d_out, int out_size, void* d_ws, size_t ws_size,
                              hipStream_t stream)
{
    (void)in_sizes; (void)n_in; (void)out_size; (void)ws_size;
    const float* text = (const float*)d_in[0];   // [64,128,768] fp32
    const float* img  = (const float*)d_in[1];   // [64, 64,768] fp32
    const int*   tm   = (const int*)d_in[2];     // [64,128] int32
    const int*   im   = (const int*)d_in[3];     // [64, 64] int32
    float* out = (float*)d_out;                  // [1 + 64*128*768] fp32

    // workspace layout (bytes); total ~21 MB
    char* ws = (char*)d_ws;
    unsigned short* A = (unsigned short*)(ws);                   // 12.58 MB fp16
    unsigned short* B = (unsigned short*)(ws + 12582912);        //  6.29 MB fp16
    float* S = (float*)(ws + 18874368);                          // 16 KB
    float* W = (float*)(ws + 18890752);                          //  2 MB

    k_prep<<<(TQ + IQ) / 256, 256, 0, stream>>>(
        (const float4*)text, (const float4*)img, (ushort4*)A, (ushort4*)B);

    k_scores<<<BSZ * (BSZ / 2), 256, 0, stream>>>(A, B, tm, im, S, W);

    dim3 g2(BSZ, 3, 8);
    k_i2s<<<g2, 256, 0, stream>>>(W, img, out);

    k_loss<<<1, 64, 0, stream>>>(S, out);
}